// Round 2
// baseline (610.924 us; speedup 1.0000x reference)
//
#include <hip/hip_runtime.h>
#include <math.h>

#define B      32
#define S      4096
#define H      1024
#define NSPANS 16
#define NCLS   25

// ---------------------------------------------------------------------------
// K1: per-span scaled sums. Grid (NSPANS, B), block 256.
// Wave 0 derives validity ("break at first (0,0)") lane-parallel via ballot.
// Each block writes its span's scale*sum into its OWN spanbuf slot
// (zeros if invalid) -> no atomics, no pre-zero memset needed.
// ---------------------------------------------------------------------------
__global__ __launch_bounds__(256) void span_pool_kernel(
    const float* __restrict__ emb,       // [B,S,H]
    const int*   __restrict__ spans,     // [B,NSPANS,2]
    float*       __restrict__ spanbuf)   // [B,NSPANS,H]
{
    const int n = blockIdx.x;
    const int b = blockIdx.y;

    __shared__ int   sh_s0, sh_s1, sh_valid;
    __shared__ float sh_scale;

    if (threadIdx.x < 64) {
        const int k = threadIdx.x;
        int a = 0, e = 0;
        if (k < NSPANS) {
            a = spans[(b * NSPANS + k) * 2 + 0];
            e = spans[(b * NSPANS + k) * 2 + 1];
        }
        // lanes >= NSPANS have a=e=0 -> bit clear in nzmask
        unsigned long long nzmask = __ballot((a | e) != 0);
        // first (0,0) row == first zero bit (torch 'break' semantics)
        const int nvalid = (int)__builtin_ctzll(~nzmask);   // in [0, NSPANS]

        int len = (k < nvalid) ? (e - a) : 0;
        #pragma unroll
        for (int off = 32; off > 0; off >>= 1)
            len += __shfl_down(len, off, 64);               // lane 0: total

        if (k == 0) {
            sh_scale = (len > 0) ? (1.0f / (float)len) : 0.0f;
            sh_valid = (n < nvalid);
        }
        if (k == n) { sh_s0 = a; sh_s1 = e; }
    }
    __syncthreads();

    float4 r = make_float4(0.f, 0.f, 0.f, 0.f);

    if (sh_valid) {
        const int   s0    = sh_s0;
        const int   s1    = sh_s1;
        const float scale = sh_scale;

        const float4* base =
            (const float4*)(emb + (size_t)b * S * H) + threadIdx.x;

        float4 a0 = make_float4(0.f, 0.f, 0.f, 0.f);
        float4 a1 = make_float4(0.f, 0.f, 0.f, 0.f);
        float4 a2 = make_float4(0.f, 0.f, 0.f, 0.f);
        float4 a3 = make_float4(0.f, 0.f, 0.f, 0.f);

        int t = s0;
        for (; t + 4 <= s1; t += 4) {
            float4 v0 = base[(size_t)(t + 0) * (H / 4)];
            float4 v1 = base[(size_t)(t + 1) * (H / 4)];
            float4 v2 = base[(size_t)(t + 2) * (H / 4)];
            float4 v3 = base[(size_t)(t + 3) * (H / 4)];
            a0.x += v0.x; a0.y += v0.y; a0.z += v0.z; a0.w += v0.w;
            a1.x += v1.x; a1.y += v1.y; a1.z += v1.z; a1.w += v1.w;
            a2.x += v2.x; a2.y += v2.y; a2.z += v2.z; a2.w += v2.w;
            a3.x += v3.x; a3.y += v3.y; a3.z += v3.z; a3.w += v3.w;
        }
        for (; t < s1; ++t) {
            float4 v = base[(size_t)t * (H / 4)];
            a0.x += v.x; a0.y += v.y; a0.z += v.z; a0.w += v.w;
        }

        r.x = (a0.x + a1.x + a2.x + a3.x) * scale;
        r.y = (a0.y + a1.y + a2.y + a3.y) * scale;
        r.z = (a0.z + a1.z + a2.z + a3.z) * scale;
        r.w = (a0.w + a1.w + a2.w + a3.w) * scale;
    }

    float4* dst = (float4*)(spanbuf + ((size_t)b * NSPANS + n) * H);
    dst[threadIdx.x] = r;
}

// ---------------------------------------------------------------------------
// K2: h = relu(pooled @ W1 + b1), batched 2 rows per block.
// Grid 256 = 16 batch-pairs x 16 j-blocks of 64 outputs. Each W1 load is
// reused for 2 batches (halves L2 traffic vs per-batch GEMV); pooled rows
// rebuilt from spanbuf in LDS (L2-resident, ~1 us total).
// ---------------------------------------------------------------------------
__global__ __launch_bounds__(256) void fc1_relu_kernel(
    const float* __restrict__ spanbuf,   // [B,NSPANS,H]
    const float* __restrict__ W1,        // [H,H] row-major
    const float* __restrict__ b1,        // [H]
    float*       __restrict__ hbuf)      // [B,H]
{
    const int bp   = blockIdx.x >> 4;            // batch pair 0..15
    const int jblk = (blockIdx.x & 15) << 6;     // 64 outputs per block
    const int b0   = bp * 2;
    const int bb1  = bp * 2 + 1;

    __shared__ float pool0[H];
    __shared__ float pool1[H];

    {   // reduce 16 span slots -> pooled rows for both batches
        const float4* s0 =
            (const float4*)(spanbuf + (size_t)b0 * NSPANS * H) + threadIdx.x;
        const float4* s1 =
            (const float4*)(spanbuf + (size_t)bb1 * NSPANS * H) + threadIdx.x;
        float4 acc0 = make_float4(0.f, 0.f, 0.f, 0.f);
        float4 acc1 = make_float4(0.f, 0.f, 0.f, 0.f);
        #pragma unroll
        for (int nn = 0; nn < NSPANS; ++nn) {
            float4 v0 = s0[nn * (H / 4)];
            float4 v1 = s1[nn * (H / 4)];
            acc0.x += v0.x; acc0.y += v0.y; acc0.z += v0.z; acc0.w += v0.w;
            acc1.x += v1.x; acc1.y += v1.y; acc1.z += v1.z; acc1.w += v1.w;
        }
        ((float4*)pool0)[threadIdx.x] = acc0;
        ((float4*)pool1)[threadIdx.x] = acc1;
    }
    __syncthreads();

    const int lane = threadIdx.x & 63;
    const int quad = threadIdx.x >> 6;           // wave id = i-quarter
    const int j    = jblk + lane;

    const float* w = W1 + j;
    float a0 = 0.0f, a1 = 0.0f;
    const int i0 = quad * (H / 4);
    #pragma unroll 8
    for (int i = i0; i < i0 + H / 4; ++i) {
        const float wv = w[(size_t)i * H];
        a0 = fmaf(pool0[i], wv, a0);
        a1 = fmaf(pool1[i], wv, a1);
    }

    __shared__ float part[2][4][64];
    part[0][quad][lane] = a0;
    part[1][quad][lane] = a1;
    __syncthreads();

    if (threadIdx.x < 128) {
        const int bb = threadIdx.x >> 6;         // 0 or 1
        const int l  = threadIdx.x & 63;
        float s = part[bb][0][l] + part[bb][1][l]
                + part[bb][2][l] + part[bb][3][l] + b1[jblk + l];
        hbuf[(size_t)(b0 + bb) * H + jblk + l] = fmaxf(s, 0.0f);
    }
}

// ---------------------------------------------------------------------------
// K3: out = sigmoid(h @ W2 + b2).  Grid (NCLS, B), block 256.
// Wave shuffle reduce (width 64) then LDS across the 4 waves.
// ---------------------------------------------------------------------------
__global__ __launch_bounds__(256) void fc2_sigmoid_kernel(
    const float* __restrict__ hbuf,      // [B,H]
    const float* __restrict__ W2,        // [H,NCLS]
    const float* __restrict__ b2,        // [NCLS]
    float*       __restrict__ out)       // [B,NCLS]
{
    const int c = blockIdx.x;
    const int b = blockIdx.y;

    const float* hrow = hbuf + (size_t)b * H;
    float partial = 0.0f;
    #pragma unroll
    for (int i = threadIdx.x; i < H; i += 256) {
        partial = fmaf(hrow[i], W2[(size_t)i * NCLS + c], partial);
    }

    #pragma unroll
    for (int off = 32; off > 0; off >>= 1)
        partial += __shfl_down(partial, off, 64);

    __shared__ float wsum[4];
    const int wave = threadIdx.x >> 6;
    const int lane = threadIdx.x & 63;
    if (lane == 0) wsum[wave] = partial;
    __syncthreads();

    if (threadIdx.x == 0) {
        float s = wsum[0] + wsum[1] + wsum[2] + wsum[3] + b2[c];
        out[(size_t)b * NCLS + c] = 1.0f / (1.0f + expf(-s));
    }
}

// ---------------------------------------------------------------------------
extern "C" void kernel_launch(void* const* d_in, const int* in_sizes, int n_in,
                              void* d_out, int out_size, void* d_ws, size_t ws_size,
                              hipStream_t stream) {
    const float* emb   = (const float*)d_in[0];
    const int*   spans = (const int*)  d_in[1];
    const float* W1    = (const float*)d_in[2];
    const float* b1    = (const float*)d_in[3];
    const float* W2    = (const float*)d_in[4];
    const float* b2    = (const float*)d_in[5];
    float*       out   = (float*)d_out;

    float* spanbuf = (float*)d_ws;               // B*NSPANS*H floats = 2 MB
    float* hbuf    = spanbuf + (size_t)B * NSPANS * H;  // B*H floats = 128 KB

    // no memset: every spanbuf slot is written by K1 (zeros for invalid spans)

    span_pool_kernel<<<dim3(NSPANS, B), 256, 0, stream>>>(emb, spans, spanbuf);
    fc1_relu_kernel<<<dim3(256), 256, 0, stream>>>(spanbuf, W1, b1, hbuf);
    fc2_sigmoid_kernel<<<dim3(NCLS, B), 256, 0, stream>>>(hbuf, W2, b2, out);
}